// Round 2
// baseline (120.684 us; speedup 1.0000x reference)
//
#include <hip/hip_runtime.h>
#include <math.h>

#define Bc 8
#define Hc 128
#define Wc 128
#define Cc 20
#define Gc 64
#define HWc (Hc*Wc)          // 16384
#define NBLK (Bc*HWc/256)    // 512 main blocks, 64 per image

// ws layout: per-block partials, 8 floats per block (6 used), written
// unconditionally every iteration -> no zero-init / poison dependency.

__device__ __forceinline__ float wave_sum(float v) {
  #pragma unroll
  for (int o = 32; o > 0; o >>= 1) v += __shfl_down(v, o, 64);
  return v;
}

__global__ __launch_bounds__(256, 2) void main_kernel(
    const float* __restrict__ kpt, const float* __restrict__ preg,
    const float* __restrict__ fpn, const float* __restrict__ masks,
    const float* __restrict__ gt,  const float* __restrict__ sy,
    const float* __restrict__ sx,  float* __restrict__ ws)
{
  __shared__ float s_kpt[Cc*256];       // transposed [c][p] 20 KB
  __shared__ float s_fpn[Cc*256];       // transposed [c][p] 20 KB
  __shared__ float s_masks[16*256];     // one 16-g chunk, [g][p] 16 KB
  __shared__ float4 s_red[Gc];          // class-sorted (fgy,fgx,.5/sy,.5/sx)
  __shared__ int s_kpix[Gc];            // class-sorted keypoint pixel
  __shared__ int s_seg[Gc];             // original-order class id (or 20)
  __shared__ int s_starts[Cc+2];
  __shared__ int s_counts[Cc+1];
  __shared__ int s_offs[Cc+1];
  __shared__ int s_nslice;
  __shared__ float s_part[4][6];

  const int T = threadIdx.x;
  const int b = blockIdx.x >> 6;
  const int pixbase = blockIdx.x * 256;
  const int pix = pixbase + T;
  const int hw = pix & (HWc-1);
  const int h = hw >> 7, w = hw & (Wc-1);

  // ---- issue staging loads into registers (coalesced) ----
  const float4* __restrict__ kg4 = (const float4*)(kpt + (size_t)pixbase*Cc);
  const float4* __restrict__ fg4 = (const float4*)(fpn + (size_t)pixbase*Cc);
  const float4* __restrict__ mg4 = (const float4*)(masks + (size_t)pixbase*Gc);
  float4 kpr[5], fpr[5], mpr[4];
  #pragma unroll
  for (int k = 0; k < 5; ++k) { kpr[k] = kg4[T + 256*k]; fpr[k] = fg4[T + 256*k]; }
  #pragma unroll
  for (int k = 0; k < 4; ++k) mpr[k] = mg4[((T>>2) + 64*k)*16 + (T&3)];   // chunk 0

  // ---- per-block prep for image b (wave 0 does the gt work) ----
  if (T < Cc+1) { s_counts[T] = 0; s_offs[T] = 0; }
  float cy = 0.f, cx = 0.f; int cls = Cc; bool valid = false;
  if (T < 64) {
    const float* grow = gt + (size_t)(b*Gc + T)*7;
    cy = grow[0]; cx = grow[1];
    // wave argmin over cy, first-index tie-break (== jnp.argmin)
    float v = cy; int idx = T;
    #pragma unroll
    for (int o = 32; o > 0; o >>= 1) {
      const float ov = __shfl_down(v, o, 64);
      const int   oi = __shfl_down(idx, o, 64);
      if (ov < v || (ov == v && oi < idx)) { v = ov; idx = oi; }
    }
    const int slice = __shfl(idx, 0, 64);
    const int cid = (int)grow[6] - 1;
    cls = (cid >= 0 && cid < Cc) ? cid : Cc;
    valid = T < slice;
    s_seg[T] = (valid && cls < Cc) ? cls : Cc;
    if (T == 0) s_nslice = slice;
  }
  __syncthreads();
  if (T < 64 && valid) atomicAdd(&s_counts[cls], 1);
  __syncthreads();
  if (T == 0) {
    int acc = 0;
    #pragma unroll
    for (int c = 0; c < Cc+1; ++c) { s_starts[c] = acc; acc += s_counts[c]; }
    s_starts[Cc+1] = acc;
  }
  __syncthreads();
  if (T < 64 && valid) {
    const int pos = s_starts[cls] + atomicAdd(&s_offs[cls], 1); // bucket order irrelevant
    float4 rp;
    rp.x = floorf((cy + 0.5f)*0.25f);
    rp.y = floorf((cx + 0.5f)*0.25f);
    rp.z = 0.5f / sy[b*Gc + T];
    rp.w = 0.5f / sx[b*Gc + T];
    s_red[pos] = rp;
    int kpy = (int)floorf(cy*0.25f); kpy = kpy < 0 ? 0 : (kpy > Hc-1 ? Hc-1 : kpy);
    int kpx = (int)floorf(cx*0.25f); kpx = kpx < 0 ? 0 : (kpx > Wc-1 ? Wc-1 : kpx);
    s_kpix[pos] = kpy*Wc + kpx;
  }

  // ---- scatter staged regs -> LDS (transposed, conflict-free reads later) ----
  #pragma unroll
  for (int k = 0; k < 5; ++k) {
    const int base = (T + 256*k)*4;
    const float ke[4] = {kpr[k].x, kpr[k].y, kpr[k].z, kpr[k].w};
    const float fe[4] = {fpr[k].x, fpr[k].y, fpr[k].z, fpr[k].w};
    #pragma unroll
    for (int i = 0; i < 4; ++i) {
      const int li = base + i;
      const int p = li / 20;
      const int c = li - p*20;
      s_kpt[c*256 + p] = ke[i];
      s_fpn[c*256 + p] = fe[i];
    }
  }
  #pragma unroll
  for (int k = 0; k < 4; ++k) {
    const int p  = (T>>2) + 64*k;
    const int g0 = (T&3)*4;
    const float me[4] = {mpr[k].x, mpr[k].y, mpr[k].z, mpr[k].w};
    #pragma unroll
    for (int i = 0; i < 4; ++i) s_masks[(g0+i)*256 + p] = me[i];
  }
  // prefetch mask chunk 1 (always in-bounds: full 64-g rows exist)
  #pragma unroll
  for (int k = 0; k < 4; ++k) mpr[k] = mg4[((T>>2) + 64*k)*16 + 4 + (T&3)];
  __syncthreads();

  const int nslice = s_nslice;
  const int nch = (nslice + 15) >> 4;

  const float wx = w + 0.5f, hy = h + 0.5f;
  // fold (gt+0.5)*0.25 into one fma per side; bit-identical (all terms exact)
  const float wxp = wx - 0.125f, wxm = 0.125f - wx;
  const float hyp = hy - 0.125f, hym = 0.125f - hy;
  const float px_ = (float)w, py_ = (float)h;

  // ---- pass 1: argmin over valid gts; boxes via uniform s_load from gt ----
  float amin = 3.0e38f, loc = 0.f, mmin = 0.f; int gmin = 0;
  for (int cc = 0; cc < nch; ++cc) {
    const int rem = nslice - cc*16;
    const int gend = rem < 16 ? rem : 16;
    for (int gl = 0; gl < gend; ++gl) {
      const int g = cc*16 + gl;
      const float* grow = gt + (size_t)(b*Gc + g)*7;   // uniform -> s_load
      const float m = s_masks[gl*256 + T];
      const float dl = fmaf(-0.25f, grow[3], wxp);
      const float dr = fmaf( 0.25f, grow[5], wxm);
      const float dt = fmaf(-0.25f, grow[2], hyp);
      const float db = fmaf( 0.25f, grow[4], hym);
      const bool inb = (dl > 0.f) & (dr > 0.f) & (dt > 0.f) & (db > 0.f);
      const float hm = inb ? m : 0.f;
      const float area = (dl*hm + dr*hm) * (dt*hm + db*hm);
      const float ap = area + (1.f - hm)*1e8f;
      if (ap < amin) { amin = ap; gmin = g; mmin = m; }
      loc = fmaxf(loc, hm);
    }
    if (cc + 1 < nch) {
      __syncthreads();                        // readers of chunk cc done
      #pragma unroll
      for (int k = 0; k < 4; ++k) {
        const int p  = (T>>2) + 64*k;
        const int g0 = (T&3)*4;
        const float me[4] = {mpr[k].x, mpr[k].y, mpr[k].z, mpr[k].w};
        #pragma unroll
        for (int i = 0; i < 4; ++i) s_masks[(g0+i)*256 + p] = me[i];
      }
      if (cc + 2 < nch) {
        #pragma unroll
        for (int k = 0; k < 4; ++k)
          mpr[k] = mg4[((T>>2) + 64*k)*16 + (cc+2)*4 + (T&3)];
      }
      __syncthreads();                        // chunk cc+1 visible
    }
  }

  // ---- dist_mask nonzero only at gmin (recompute, bit-identical fmas) ----
  float dlm=0.f, drm=0.f, dtm=0.f, dbm=0.f, hmval=0.f; int cmin = Cc;
  if (loc > 0.f) {
    const float* gr = gt + (size_t)(b*Gc + gmin)*7;    // per-thread, L1/L2-hot
    const float dl = fmaf(-0.25f, gr[3], wxp);
    const float dr = fmaf( 0.25f, gr[5], wxm);
    const float dt = fmaf(-0.25f, gr[2], hyp);
    const float db = fmaf( 0.25f, gr[4], hym);
    const float area = (dl*mmin + dr*mmin) * (dt*mmin + db*mmin);
    if (area == amin) {
      dlm = dl*mmin*loc; drm = dr*mmin*loc; dtm = dt*mmin*loc; dbm = db*mmin*loc;
      cmin = s_seg[gmin];
      hmval = loc;
    }
  }

  // ---- pass 2: class buckets; exp-of-max (one exp per class) ----
  float gargmax = -1e30f, grav = 0.f, hneg = 0.f;
  int sb = s_starts[0];
  for (int c = 0; c < Cc; ++c) {
    const int s1 = s_starts[c+1];
    float ramax = -1e30f; bool kpv = false;
    for (int i = sb; i < s1; ++i) {            // wave-uniform bounds
      const float4 rp = s_red[i];              // uniform -> LDS broadcast
      const int kpix = s_kpix[i];
      const float dy = py_ - rp.x, dx = px_ - rp.y;
      const float arg = -(dy*dy*rp.z + dx*dx*rp.w);
      ramax = fmaxf(ramax, arg);
      kpv = kpv | (kpix == hw);
    }
    sb = s1;
    const float rmax = __expf(ramax);          // 0 exactly for empty bucket
    gargmax = fmaxf(gargmax, ramax);

    const float x  = s_kpt[c*256 + T];         // conflict-free LDS read
    const float e  = __expf(-fabsf(x));
    const float t  = 1.f + e;
    const float r  = 1.f / t;
    const float Lt = __logf(t);
    const float s  = (x >= 0.f) ? r : e*r;
    const float lsx = fminf(x, 0.f) - Lt;
    const float kv = kpv ? 1.f : 0.f;
    const float om = 1.f - rmax;
    const float om4 = (om*om)*(om*om);
    const float oms = 1.f - s;
    grav += (-(oms*oms)*lsx)*kv + (-om4*(s*s)*(lsx - x))*(1.f - kv);

    const float fx  = s_fpn[c*256 + T];
    const float ef  = __expf(-fabsf(fx));
    const float tf  = 1.f + ef;
    const float rf  = 1.f / tf;
    const float Lf  = __logf(tf);
    const float sf  = (fx >= 0.f) ? rf : ef*rf;
    const float lsf = fminf(fx, 0.f) - Lf;
    hneg += -10.f*(sf*sf)*(lsf - fx);          // hg=0 baseline; fixed up below
  }
  {
    const int e20 = s_starts[Cc+1];
    for (int i = sb; i < e20; ++i) {           // bucket 20: iou_red arg only
      const float4 rp = s_red[i];
      const float dy = py_ - rp.x, dx = px_ - rp.y;
      gargmax = fmaxf(gargmax, -(dy*dy*rp.z + dx*dx*rp.w));
    }
  }
  const float iou_red = __expf(gargmax);       // 0 exactly if no valid gts

  // ---- iou term ----
  const float4 p4 = *(const float4*)(preg + (size_t)pix*4);
  const float inter = (fminf(dlm,p4.x)+fminf(drm,p4.y)) * (fminf(dtm,p4.z)+fminf(dbm,p4.w));
  const float uni = (dlm+drm)*(dtm+dbm) + (p4.x+p4.y)*(p4.z+p4.w) - inter;
  const float iou = inter / (uni + 1e-12f);
  const float t_iou = -__logf(iou + 1e-12f) * loc * (iou_red*4.f + 1.f);

  // ---- hm fixup at cmin (LDS re-read) ----
  float hpos = 0.f, shg = 0.f;
  if (hmval > 0.f && cmin < Cc) {
    const float fx  = s_fpn[cmin*256 + T];
    const float ef  = __expf(-fabsf(fx));
    const float tf  = 1.f + ef;
    const float rf  = 1.f / tf;
    const float Lf  = __logf(tf);
    const float sf  = (fx >= 0.f) ? rf : ef*rf;
    const float lsf = fminf(fx, 0.f) - Lf;
    const float osf = 1.f - sf;
    hpos = -10.f*(osf*osf)*lsf*hmval;
    hneg -= (-10.f*(sf*sf)*(lsf - fx))*hmval;
    shg = hmval;
  }

  // ---- block reduction, per-block partials (no atomics, no zero-init) ----
  float v0 = wave_sum(t_iou);
  float v1 = wave_sum(loc);
  float v2 = wave_sum(grav);
  float v3 = wave_sum(hpos);
  float v4 = wave_sum(hneg);
  float v5 = wave_sum(shg);
  const int wv = T >> 6, ln = T & 63;
  if (ln == 0) {
    s_part[wv][0]=v0; s_part[wv][1]=v1; s_part[wv][2]=v2;
    s_part[wv][3]=v3; s_part[wv][4]=v4; s_part[wv][5]=v5;
  }
  __syncthreads();
  if (T < 6)
    ws[(size_t)blockIdx.x*8 + T] =
        s_part[0][T] + s_part[1][T] + s_part[2][T] + s_part[3][T];
}

__global__ __launch_bounds__(256) void fin_kernel(
    const float* __restrict__ gt, const float* __restrict__ ws,
    float* __restrict__ out)
{
  const int T = threadIdx.x, wv = T >> 6, ln = T & 63;
  __shared__ float s_tot[Bc];
  #pragma unroll
  for (int rep = 0; rep < 2; ++rep) {
    const int b = wv + 4*rep;
    // recompute slice for image b (same argmin as main)
    const float cy = gt[(size_t)(b*Gc + ln)*7];
    float v = cy; int idx = ln;
    #pragma unroll
    for (int o = 32; o > 0; o >>= 1) {
      const float ov = __shfl_down(v, o, 64);
      const int   oi = __shfl_down(idx, o, 64);
      if (ov < v || (ov == v && oi < idx)) { v = ov; idx = oi; }
    }
    const int slice = __shfl(idx, 0, 64);
    // sum this image's 64 block-partials
    const float* pb = ws + (size_t)(b*64 + ln)*8;
    const float a0 = wave_sum(pb[0]);
    const float a1 = wave_sum(pb[1]);
    const float a2 = wave_sum(pb[2]);
    const float a3 = wave_sum(pb[3]);
    const float a4 = wave_sum(pb[4]);
    const float a5 = wave_sum(pb[5]);
    if (ln == 0) {
      const float nv       = fmaxf((float)slice, 1.0f);
      const float hm_loss  = a4 / ((float)(HWc*Cc) - a5);
      const bool  cond     = (a5 != 0.0f);
      const float safe_hg  = cond ? a5 : 1.0f;
      const float safe_loc = (a1 > 0.0f) ? a1 : 1.0f;
      const float hm2      = hm_loss + a3/safe_hg;
      s_tot[b] = cond ? (a0/safe_loc + a2/nv + hm2) : hm_loss;
    }
  }
  __syncthreads();
  if (T == 0) {
    float s = 0.f;
    #pragma unroll
    for (int i = 0; i < Bc; ++i) s += s_tot[i];
    out[0] = s * (1.0f/(float)Bc);
  }
}

extern "C" void kernel_launch(void* const* d_in, const int* in_sizes, int n_in,
                              void* d_out, int out_size, void* d_ws, size_t ws_size,
                              hipStream_t stream) {
  const float* kpt  = (const float*)d_in[0];  // keypoints  [B,H,W,C]
  const float* preg = (const float*)d_in[1];  // preg       [B,H,W,4]
  const float* fpn  = (const float*)d_in[2];  // fpn        [B,H,W,C]
  const float* gt   = (const float*)d_in[3];  // gt         [B,G,7]
  const float* mk   = (const float*)d_in[4];  // masks      [B,H,W,G]
  const float* sy   = (const float*)d_in[5];  // scalar_y   [B,G]
  const float* sx   = (const float*)d_in[6];  // scalar_x   [B,G]
  float* ws  = (float*)d_ws;
  float* out = (float*)d_out;

  main_kernel<<<NBLK, 256, 0, stream>>>(kpt, preg, fpn, mk, gt, sy, sx, ws);
  fin_kernel<<<1, 256, 0, stream>>>(ws ? gt : gt, ws, out);
}